// Round 9
// baseline (98.671 us; speedup 1.0000x reference)
//
#include <hip/hip_runtime.h>

// Coords are all {0,1}; STRIDES is a mixed-radix positional encoding, so each
// row maps bijectively to a 16-bit pattern. Whole op = 65536-bin float
// histogram + gather.
//
// R0-R2: global fp32 atomicAdd executes at the memory-side coherence point
// regardless of scope (~19G ops/s cap) -> no global atomics anywhere.
// R4: LDS-partitioned build (8 parts x 8192 bins).
// R6: int4-per-thread + 4-lane __shfl_xor nibble combine = coalesced extract.
// R7 lesson: sequential phases in one kernel SUM (all blocks/waves lockstep).
// R8: wave specialization in build: 4 waves stream the query chunk (HBM-bound)
// CONCURRENTLY with 12 waves doing the LDS histogram (latency-bound) -> max,
// not sum.

#define REL_W 16
#define NBINS 65536
#define NPART 8
#define BPP 8192        // bins per partition (32 KB as floats)
#define NSLICES 64
#define BUILD_BLK 1024
#define QTHREADS 256    // 4 waves stream queries; 12 waves build hist
#define BLK 256

typedef unsigned short ushort8_t __attribute__((ext_vector_type(8)));

__device__ __forceinline__ unsigned pattern_of(const int* __restrict__ row) {
    const int4* p = reinterpret_cast<const int4*>(row);
    unsigned pat = 0;
#pragma unroll
    for (int k = 0; k < 4; ++k) {
        int4 v = p[k];
        pat |= (unsigned)(v.x & 1) << (k * 4 + 0);
        pat |= (unsigned)(v.y & 1) << (k * 4 + 1);
        pat |= (unsigned)(v.z & 1) << (k * 4 + 2);
        pat |= (unsigned)(v.w & 1) << (k * 4 + 3);
    }
    return pat;
}

__device__ __forceinline__ unsigned nibble_of(int4 v) {
    return (unsigned)(v.x & 1) | ((unsigned)(v.y & 1) << 1) |
           ((unsigned)(v.z & 1) << 2) | ((unsigned)(v.w & 1) << 3);
}

// one thread per int4 (quarter-row); 4-lane group -> one u16 pattern
__global__ __launch_bounds__(BLK) void extract_stored(const int* __restrict__ coords,
                                                      unsigned short* __restrict__ pats, int n) {
    int g = blockIdx.x * blockDim.x + threadIdx.x;
    int total = n * 4;
    if (g < total) {
        int4 v = reinterpret_cast<const int4*>(coords)[g];
        unsigned k = (unsigned)g & 3;
        unsigned val = nibble_of(v) << (4 * k);
        val |= __shfl_xor(val, 1);
        val |= __shfl_xor(val, 2);
        if (k == 0) pats[g >> 2] = (unsigned short)val;
    }
}

// build: waves [0..3] stream query-pattern extraction; waves [4..15] build the
// (partition, slice) LDS histogram. Concurrent between the same barriers.
__global__ __launch_bounds__(BUILD_BLK) void build_qx(const unsigned short* __restrict__ pats,
                                                      const float* __restrict__ vals,
                                                      float* __restrict__ part_hists, int n,
                                                      const int* __restrict__ queries,
                                                      unsigned short* __restrict__ pat_q, int nq) {
    __shared__ float lh[BPP];
    unsigned part  = blockIdx.x / NSLICES;
    unsigned slice = blockIdx.x % NSLICES;
    for (int b = threadIdx.x; b < BPP; b += BUILD_BLK) lh[b] = 0.0f;
    __syncthreads();

    if (threadIdx.x < QTHREADS) {
        // --- query-streamer waves: extract this block's query chunk ---
        int totq = nq * 4;                               // total int4s
        int nblocks = NPART * NSLICES;
        int chunk = (totq / nblocks) & ~3;
        int qlo = (int)blockIdx.x * chunk;
        int qhi = (blockIdx.x == nblocks - 1) ? totq : qlo + chunk;
        const int4* qv = reinterpret_cast<const int4*>(queries);
#pragma unroll 4
        for (int g = qlo + (int)threadIdx.x; g < qhi; g += QTHREADS) {
            int4 v = qv[g];
            unsigned k = (unsigned)g & 3;                // == threadIdx&3 (qlo,QTHREADS %4==0)
            unsigned val = nibble_of(v) << (4 * k);
            val |= __shfl_xor(val, 1);
            val |= __shfl_xor(val, 2);
            if (k == 0) pat_q[g >> 2] = (unsigned short)val;
        }
    } else {
        // --- hist waves: LDS histogram over this slice, this partition ---
        const int HT = BUILD_BLK - QTHREADS;             // 768 threads
        int ht = (int)threadIdx.x - QTHREADS;
        int per = ((n + NSLICES - 1) / NSLICES + 7) & ~7;
        int lo = (int)slice * per;
        int hi = min(n, lo + per);
        if (lo < hi) {
            int m = hi - lo;
            int nvec = m >> 3;
            const ushort8_t* pv = reinterpret_cast<const ushort8_t*>(pats + lo);
            const float4*    vv = reinterpret_cast<const float4*>(vals + lo);
            for (int v = ht; v < nvec; v += HT) {
                ushort8_t p8 = pv[v];
                float4 v0 = vv[2 * v];
                float4 v1 = vv[2 * v + 1];
                float vsc[8] = {v0.x, v0.y, v0.z, v0.w, v1.x, v1.y, v1.z, v1.w};
#pragma unroll
                for (int kk = 0; kk < 8; ++kk) {
                    unsigned pat = p8[kk];
                    if ((pat >> 13) == part)
                        atomicAdd(&lh[pat & (BPP - 1)], vsc[kk]);   // ds_add_f32, on-CU
                }
            }
            for (int i = lo + (nvec << 3) + ht; i < hi; i += HT) {
                unsigned pat = pats[i];
                if ((pat >> 13) == part)
                    atomicAdd(&lh[pat & (BPP - 1)], vals[i]);
            }
        }
    }
    __syncthreads();
    float* dst = part_hists + (size_t)blockIdx.x * BPP;
    for (int b = threadIdx.x; b < BPP; b += BUILD_BLK) dst[b] = lh[b];
}

__global__ void reduce_parts(const float* __restrict__ part_hists, float* __restrict__ final_h) {
    int g = blockIdx.x * blockDim.x + threadIdx.x;   // bin 0..65535
    unsigned part = (unsigned)g >> 13;
    unsigned b = (unsigned)g & (BPP - 1);
    const float* src = part_hists + ((size_t)part * NSLICES) * BPP + b;
    float s = 0.0f;
#pragma unroll 8
    for (int sl = 0; sl < NSLICES; ++sl) s += src[(size_t)sl * BPP];
    final_h[g] = s;
}

// tiny final gather: 4 queries per thread via ushort4 + float4 store
__global__ __launch_bounds__(BLK) void gather_pat(const unsigned short* __restrict__ pq,
                                                  const float* __restrict__ h,
                                                  float* __restrict__ out, int n) {
    int t = blockIdx.x * blockDim.x + threadIdx.x;
    int base = t * 4;
    if (base + 4 <= n) {
        ushort4 p4 = *reinterpret_cast<const ushort4*>(pq + base);
        float4 o;
        o.x = h[p4.x]; o.y = h[p4.y]; o.z = h[p4.z]; o.w = h[p4.w];
        *reinterpret_cast<float4*>(out + base) = o;
    } else {
        for (int i = base; i < n; ++i) out[i] = h[pq[i]];
    }
}

// ---- fallback (R0 path) if workspace too small ----
__global__ void build_hist_dev(const int* __restrict__ coords, const float* __restrict__ vals,
                               float* __restrict__ hist, int n) {
    int i = blockIdx.x * blockDim.x + threadIdx.x;
    if (i >= n) return;
    atomicAdd(&hist[pattern_of(coords + (size_t)i * REL_W)], vals[i]);
}
__global__ void gather_coord(const int* __restrict__ queries, const float* __restrict__ hist,
                             float* __restrict__ out, int n) {
    int i = blockIdx.x * blockDim.x + threadIdx.x;
    if (i >= n) return;
    out[i] = hist[pattern_of(queries + (size_t)i * REL_W)];
}

static inline size_t align_up(size_t x, size_t a) { return (x + a - 1) & ~(a - 1); }

extern "C" void kernel_launch(void* const* d_in, const int* in_sizes, int n_in,
                              void* d_out, int out_size, void* d_ws, size_t ws_size,
                              hipStream_t stream) {
    const int*   stored  = (const int*)d_in[0];   // [N_store, 16] int32
    const int*   queries = (const int*)d_in[1];   // [N_query, 16] int32
    const float* vals    = (const float*)d_in[2]; // [N_store] f32
    float*       out     = (float*)d_out;         // [N_query] f32

    int n_store = in_sizes[0] / REL_W;
    int n_query = in_sizes[1] / REL_W;

    // workspace layout
    size_t off_pat_s = 0;
    size_t off_pat_q = align_up(off_pat_s + (size_t)n_store * 2, 256);
    size_t off_hists = align_up(off_pat_q + (size_t)n_query * 2, 256);
    size_t off_final = off_hists + (size_t)NPART * NSLICES * BPP * sizeof(float);
    size_t need      = off_final + (size_t)NBINS * sizeof(float);

    if (ws_size >= need) {
        unsigned short* pat_s = (unsigned short*)((char*)d_ws + off_pat_s);
        unsigned short* pat_q = (unsigned short*)((char*)d_ws + off_pat_q);
        float* part_hists     = (float*)((char*)d_ws + off_hists);
        float* final_h        = (float*)((char*)d_ws + off_final);

        int eblocks = (n_store * 4 + BLK - 1) / BLK;
        int gblocks = (n_query + BLK * 4 - 1) / (BLK * 4);
        extract_stored<<<eblocks, BLK, 0, stream>>>(stored, pat_s, n_store);
        build_qx<<<NPART * NSLICES, BUILD_BLK, 0, stream>>>(pat_s, vals, part_hists, n_store,
                                                            queries, pat_q, n_query);
        reduce_parts<<<NBINS / BLK, BLK, 0, stream>>>(part_hists, final_h);
        gather_pat<<<gblocks, BLK, 0, stream>>>(pat_q, final_h, out, n_query);
    } else {
        float* hist = (float*)d_ws;
        hipMemsetAsync(d_ws, 0, NBINS * sizeof(float), stream);
        build_hist_dev<<<(n_store + BLK - 1) / BLK, BLK, 0, stream>>>(stored, vals, hist, n_store);
        gather_coord<<<(n_query + BLK - 1) / BLK, BLK, 0, stream>>>(queries, hist, out, n_query);
    }
}

// Round 10
// 82.969 us; speedup vs baseline: 1.1892x; 1.1892x over previous
//
#include <hip/hip_runtime.h>

// Coords are all {0,1}; STRIDES is a mixed-radix positional encoding, so each
// row maps bijectively to a 16-bit pattern. Whole op = 65536-bin float
// histogram + gather.
//
// R0-R2: global fp32 atomicAdd executes at the memory-side coherence point
// regardless of scope (~19G ops/s cap) -> no global atomics anywhere.
// R4: LDS-partitioned build (8 parts x 8192 bins, 1024-thr blocks) - best.
// R6: int4-per-thread + 4-lane __shfl_xor nibble combine = coalesced extract.
// R7 lesson: sequential phases in one kernel SUM (lockstep waves).
// R8 lesson: wave-specializing two MEMORY streams contends (same VMEM path),
// doesn't overlap -> reverted.
// R9: single extract_both kernel, MLP=4 (4 independent int4 loads per thread,
// spaced BLK apart -> wave loads stay contiguous), both arrays in one pass.

#define REL_W 16
#define NBINS 65536
#define NPART 8
#define BPP 8192        // bins per partition (32 KB as floats)
#define NSLICES 64
#define BUILD_BLK 1024
#define BLK 256
#define UNROLL 4

typedef unsigned short ushort8_t __attribute__((ext_vector_type(8)));

__device__ __forceinline__ unsigned pattern_of(const int* __restrict__ row) {
    const int4* p = reinterpret_cast<const int4*>(row);
    unsigned pat = 0;
#pragma unroll
    for (int k = 0; k < 4; ++k) {
        int4 v = p[k];
        pat |= (unsigned)(v.x & 1) << (k * 4 + 0);
        pat |= (unsigned)(v.y & 1) << (k * 4 + 1);
        pat |= (unsigned)(v.z & 1) << (k * 4 + 2);
        pat |= (unsigned)(v.w & 1) << (k * 4 + 3);
    }
    return pat;
}

__device__ __forceinline__ unsigned nibble_of(int4 v) {
    return (unsigned)(v.x & 1) | ((unsigned)(v.y & 1) << 1) |
           ((unsigned)(v.z & 1) << 2) | ((unsigned)(v.w & 1) << 3);
}

// Both arrays, one thread per int4, 4 int4s per thread (independent loads).
// Window per block = BLK*UNROLL int4s; g_j = base + j*BLK keeps each wave's
// 64 lanes contiguous. Group of 4 lanes -> one u16 pattern via __shfl_xor.
// ns*4 % 4 == 0 so no 4-lane group straddles the stored/queries boundary.
__global__ __launch_bounds__(BLK) void extract_both(const int* __restrict__ stored,
                                                    const int* __restrict__ queries,
                                                    unsigned short* __restrict__ pat_s,
                                                    unsigned short* __restrict__ pat_q,
                                                    int ns, int nq) {
    const int4* sv = reinterpret_cast<const int4*>(stored);
    const int4* qv = reinterpret_cast<const int4*>(queries);
    int ns4  = ns * 4;
    int tot4 = (ns + nq) * 4;
    int base = blockIdx.x * (BLK * UNROLL) + threadIdx.x;

    int   g[UNROLL];
    int4  v[UNROLL];
#pragma unroll
    for (int j = 0; j < UNROLL; ++j) {
        g[j] = base + j * BLK;
        if (g[j] < tot4)
            v[j] = (g[j] < ns4) ? sv[g[j]] : qv[g[j] - ns4];
    }
#pragma unroll
    for (int j = 0; j < UNROLL; ++j) {
        if (g[j] < tot4) {
            unsigned k = (unsigned)g[j] & 3;          // == lane&3 (4-aligned groups)
            unsigned val = nibble_of(v[j]) << (4 * k);
            val |= __shfl_xor(val, 1);
            val |= __shfl_xor(val, 2);
            if (k == 0) {
                if (g[j] < ns4) pat_s[g[j] >> 2] = (unsigned short)val;
                else            pat_q[(g[j] - ns4) >> 2] = (unsigned short)val;
            }
        }
    }
}

__global__ __launch_bounds__(BUILD_BLK) void build_parts(const unsigned short* __restrict__ pats,
                                                         const float* __restrict__ vals,
                                                         float* __restrict__ part_hists, int n) {
    __shared__ float lh[BPP];
    unsigned part  = blockIdx.x / NSLICES;
    unsigned slice = blockIdx.x % NSLICES;
    for (int b = threadIdx.x; b < BPP; b += BUILD_BLK) lh[b] = 0.0f;
    __syncthreads();

    int per = ((n + NSLICES - 1) / NSLICES + 7) & ~7;
    int lo = (int)slice * per;
    int hi = min(n, lo + per);
    if (lo < hi) {
        int m = hi - lo;
        int nvec = m >> 3;
        const ushort8_t* pv = reinterpret_cast<const ushort8_t*>(pats + lo);
        const float4*    vv = reinterpret_cast<const float4*>(vals + lo);
        for (int v = threadIdx.x; v < nvec; v += BUILD_BLK) {
            ushort8_t p8 = pv[v];
            float4 v0 = vv[2 * v];
            float4 v1 = vv[2 * v + 1];
            float vsc[8] = {v0.x, v0.y, v0.z, v0.w, v1.x, v1.y, v1.z, v1.w};
#pragma unroll
            for (int kk = 0; kk < 8; ++kk) {
                unsigned pat = p8[kk];
                if ((pat >> 13) == part)
                    atomicAdd(&lh[pat & (BPP - 1)], vsc[kk]);   // ds_add_f32, on-CU
            }
        }
        for (int i = lo + (nvec << 3) + (int)threadIdx.x; i < hi; i += BUILD_BLK) {
            unsigned pat = pats[i];
            if ((pat >> 13) == part)
                atomicAdd(&lh[pat & (BPP - 1)], vals[i]);
        }
    }
    __syncthreads();
    float* dst = part_hists + (size_t)blockIdx.x * BPP;
    for (int b = threadIdx.x; b < BPP; b += BUILD_BLK) dst[b] = lh[b];
}

__global__ void reduce_parts(const float* __restrict__ part_hists, float* __restrict__ final_h) {
    int g = blockIdx.x * blockDim.x + threadIdx.x;   // bin 0..65535
    unsigned part = (unsigned)g >> 13;
    unsigned b = (unsigned)g & (BPP - 1);
    const float* src = part_hists + ((size_t)part * NSLICES) * BPP + b;
    float s = 0.0f;
#pragma unroll 8
    for (int sl = 0; sl < NSLICES; ++sl) s += src[(size_t)sl * BPP];
    final_h[g] = s;
}

// tiny final gather: 4 queries per thread via ushort4 + float4 store
__global__ __launch_bounds__(BLK) void gather_pat(const unsigned short* __restrict__ pq,
                                                  const float* __restrict__ h,
                                                  float* __restrict__ out, int n) {
    int t = blockIdx.x * blockDim.x + threadIdx.x;
    int base = t * 4;
    if (base + 4 <= n) {
        ushort4 p4 = *reinterpret_cast<const ushort4*>(pq + base);
        float4 o;
        o.x = h[p4.x]; o.y = h[p4.y]; o.z = h[p4.z]; o.w = h[p4.w];
        *reinterpret_cast<float4*>(out + base) = o;
    } else {
        for (int i = base; i < n; ++i) out[i] = h[pq[i]];
    }
}

// ---- fallback (R0 path) if workspace too small ----
__global__ void build_hist_dev(const int* __restrict__ coords, const float* __restrict__ vals,
                               float* __restrict__ hist, int n) {
    int i = blockIdx.x * blockDim.x + threadIdx.x;
    if (i >= n) return;
    atomicAdd(&hist[pattern_of(coords + (size_t)i * REL_W)], vals[i]);
}
__global__ void gather_coord(const int* __restrict__ queries, const float* __restrict__ hist,
                             float* __restrict__ out, int n) {
    int i = blockIdx.x * blockDim.x + threadIdx.x;
    if (i >= n) return;
    out[i] = hist[pattern_of(queries + (size_t)i * REL_W)];
}

static inline size_t align_up(size_t x, size_t a) { return (x + a - 1) & ~(a - 1); }

extern "C" void kernel_launch(void* const* d_in, const int* in_sizes, int n_in,
                              void* d_out, int out_size, void* d_ws, size_t ws_size,
                              hipStream_t stream) {
    const int*   stored  = (const int*)d_in[0];   // [N_store, 16] int32
    const int*   queries = (const int*)d_in[1];   // [N_query, 16] int32
    const float* vals    = (const float*)d_in[2]; // [N_store] f32
    float*       out     = (float*)d_out;         // [N_query] f32

    int n_store = in_sizes[0] / REL_W;
    int n_query = in_sizes[1] / REL_W;

    // workspace layout
    size_t off_pat_s = 0;
    size_t off_pat_q = align_up(off_pat_s + (size_t)n_store * 2, 256);
    size_t off_hists = align_up(off_pat_q + (size_t)n_query * 2, 256);
    size_t off_final = off_hists + (size_t)NPART * NSLICES * BPP * sizeof(float);
    size_t need      = off_final + (size_t)NBINS * sizeof(float);

    if (ws_size >= need) {
        unsigned short* pat_s = (unsigned short*)((char*)d_ws + off_pat_s);
        unsigned short* pat_q = (unsigned short*)((char*)d_ws + off_pat_q);
        float* part_hists     = (float*)((char*)d_ws + off_hists);
        float* final_h        = (float*)((char*)d_ws + off_final);

        int tot4    = (n_store + n_query) * 4;
        int eblocks = (tot4 + BLK * UNROLL - 1) / (BLK * UNROLL);
        int gblocks = (n_query + BLK * 4 - 1) / (BLK * 4);
        extract_both<<<eblocks, BLK, 0, stream>>>(stored, queries, pat_s, pat_q, n_store, n_query);
        build_parts<<<NPART * NSLICES, BUILD_BLK, 0, stream>>>(pat_s, vals, part_hists, n_store);
        reduce_parts<<<NBINS / BLK, BLK, 0, stream>>>(part_hists, final_h);
        gather_pat<<<gblocks, BLK, 0, stream>>>(pat_q, final_h, out, n_query);
    } else {
        float* hist = (float*)d_ws;
        hipMemsetAsync(d_ws, 0, NBINS * sizeof(float), stream);
        build_hist_dev<<<(n_store + BLK - 1) / BLK, BLK, 0, stream>>>(stored, vals, hist, n_store);
        gather_coord<<<(n_query + BLK - 1) / BLK, BLK, 0, stream>>>(queries, hist, out, n_query);
    }
}

// Round 11
// 77.008 us; speedup vs baseline: 1.2813x; 1.0774x over previous
//
#include <hip/hip_runtime.h>

// Coords are all {0,1}; STRIDES is a mixed-radix positional encoding, so each
// row maps bijectively to a 16-bit pattern. Whole op = 65536-bin float
// histogram + gather.
//
// R0-R2: global fp32 atomicAdd executes at the memory-side coherence point
// regardless of scope (~19G ops/s cap) -> no global atomics anywhere.
// R4: LDS-partitioned build (8 parts x 8192 bins, 1024-thr blocks).
// R6/R9: int4-per-thread + 4-lane __shfl_xor nibble combine (coalesced).
// R10: every extract so far showed VGPR_Count=16 -> compiler SERIALIZED the
// loads (MLP~1.5); Little's law then caps at the observed ~2.8 TB/s. This
// version keeps 8 independent int4 loads in named registers (no per-load
// bounds check, no ?: dual-pointer in the hot path) to force real MLP.

#define REL_W 16
#define NBINS 65536
#define NPART 8
#define BPP 8192        // bins per partition (32 KB as floats)
#define NSLICES 64
#define BUILD_BLK 1024
#define BLK 256
#define EUNROLL 8       // int4s per thread in extract

typedef unsigned short ushort8_t __attribute__((ext_vector_type(8)));

__device__ __forceinline__ unsigned pattern_of(const int* __restrict__ row) {
    const int4* p = reinterpret_cast<const int4*>(row);
    unsigned pat = 0;
#pragma unroll
    for (int k = 0; k < 4; ++k) {
        int4 v = p[k];
        pat |= (unsigned)(v.x & 1) << (k * 4 + 0);
        pat |= (unsigned)(v.y & 1) << (k * 4 + 1);
        pat |= (unsigned)(v.z & 1) << (k * 4 + 2);
        pat |= (unsigned)(v.w & 1) << (k * 4 + 3);
    }
    return pat;
}

__device__ __forceinline__ unsigned nibble_of(int4 v) {
    return (unsigned)(v.x & 1) | ((unsigned)(v.y & 1) << 1) |
           ((unsigned)(v.z & 1) << 2) | ((unsigned)(v.w & 1) << 3);
}

// combine 4-lane nibbles into a u16 pattern; lane k==0 of each group stores
__device__ __forceinline__ void emit_pat(unsigned g, unsigned nib, unsigned k, unsigned sh,
                                         unsigned short* __restrict__ dst) {
    unsigned val = nib << sh;
    val |= __shfl_xor(val, 1);
    val |= __shfl_xor(val, 2);
    if (k == 0) dst[g >> 2] = (unsigned short)val;
}

// 8 int4s per thread, spaced BLK apart (wave loads contiguous: 1KB/instr).
// Source select is block-uniform except the (at most one) boundary block.
__global__ __launch_bounds__(BLK) void extract_both8(const int* __restrict__ stored,
                                                     const int* __restrict__ queries,
                                                     unsigned short* __restrict__ pat_s,
                                                     unsigned short* __restrict__ pat_q,
                                                     int ns, int nq) {
    const int4* sv = reinterpret_cast<const int4*>(stored);
    const int4* qv = reinterpret_cast<const int4*>(queries);
    int ns4  = ns * 4;
    int tot4 = (ns + nq) * 4;
    int blk_lo = blockIdx.x * (BLK * EUNROLL);
    int blk_hi = blk_lo + BLK * EUNROLL;           // exclusive
    int base   = blk_lo + (int)threadIdx.x;
    unsigned k  = (unsigned)threadIdx.x & 3;       // group index (stride BLK keeps it)
    unsigned sh = 4 * k;

    if (blk_hi <= ns4) {
        // ---- pure stored block: 8 independent loads, then process ----
        int4 v0 = sv[base + 0 * BLK], v1 = sv[base + 1 * BLK];
        int4 v2 = sv[base + 2 * BLK], v3 = sv[base + 3 * BLK];
        int4 v4 = sv[base + 4 * BLK], v5 = sv[base + 5 * BLK];
        int4 v6 = sv[base + 6 * BLK], v7 = sv[base + 7 * BLK];
        emit_pat(base + 0 * BLK, nibble_of(v0), k, sh, pat_s);
        emit_pat(base + 1 * BLK, nibble_of(v1), k, sh, pat_s);
        emit_pat(base + 2 * BLK, nibble_of(v2), k, sh, pat_s);
        emit_pat(base + 3 * BLK, nibble_of(v3), k, sh, pat_s);
        emit_pat(base + 4 * BLK, nibble_of(v4), k, sh, pat_s);
        emit_pat(base + 5 * BLK, nibble_of(v5), k, sh, pat_s);
        emit_pat(base + 6 * BLK, nibble_of(v6), k, sh, pat_s);
        emit_pat(base + 7 * BLK, nibble_of(v7), k, sh, pat_s);
    } else if (blk_lo >= ns4 && blk_hi <= tot4) {
        // ---- pure query block ----
        int b = base - ns4;
        int4 v0 = qv[b + 0 * BLK], v1 = qv[b + 1 * BLK];
        int4 v2 = qv[b + 2 * BLK], v3 = qv[b + 3 * BLK];
        int4 v4 = qv[b + 4 * BLK], v5 = qv[b + 5 * BLK];
        int4 v6 = qv[b + 6 * BLK], v7 = qv[b + 7 * BLK];
        emit_pat(b + 0 * BLK, nibble_of(v0), k, sh, pat_q);
        emit_pat(b + 1 * BLK, nibble_of(v1), k, sh, pat_q);
        emit_pat(b + 2 * BLK, nibble_of(v2), k, sh, pat_q);
        emit_pat(b + 3 * BLK, nibble_of(v3), k, sh, pat_q);
        emit_pat(b + 4 * BLK, nibble_of(v4), k, sh, pat_q);
        emit_pat(b + 5 * BLK, nibble_of(v5), k, sh, pat_q);
        emit_pat(b + 6 * BLK, nibble_of(v6), k, sh, pat_q);
        emit_pat(b + 7 * BLK, nibble_of(v7), k, sh, pat_q);
    } else {
        // ---- boundary / tail block: per-element guarded path ----
#pragma unroll
        for (int j = 0; j < EUNROLL; ++j) {
            int g = base + j * BLK;
            if (g < tot4) {
                int4 v = (g < ns4) ? sv[g] : qv[g - ns4];
                unsigned val = nibble_of(v) << sh;
                val |= __shfl_xor(val, 1);
                val |= __shfl_xor(val, 2);
                if (k == 0) {
                    if (g < ns4) pat_s[g >> 2] = (unsigned short)val;
                    else         pat_q[(g - ns4) >> 2] = (unsigned short)val;
                }
            }
        }
    }
}

__global__ __launch_bounds__(BUILD_BLK) void build_parts(const unsigned short* __restrict__ pats,
                                                         const float* __restrict__ vals,
                                                         float* __restrict__ part_hists, int n) {
    __shared__ float lh[BPP];
    unsigned part  = blockIdx.x / NSLICES;
    unsigned slice = blockIdx.x % NSLICES;
    for (int b = threadIdx.x; b < BPP; b += BUILD_BLK) lh[b] = 0.0f;
    __syncthreads();

    int per = ((n + NSLICES - 1) / NSLICES + 7) & ~7;
    int lo = (int)slice * per;
    int hi = min(n, lo + per);
    if (lo < hi) {
        int m = hi - lo;
        int nvec = m >> 3;
        const ushort8_t* pv = reinterpret_cast<const ushort8_t*>(pats + lo);
        const float4*    vv = reinterpret_cast<const float4*>(vals + lo);
        for (int v = threadIdx.x; v < nvec; v += BUILD_BLK) {
            ushort8_t p8 = pv[v];
            float4 v0 = vv[2 * v];
            float4 v1 = vv[2 * v + 1];
            float vsc[8] = {v0.x, v0.y, v0.z, v0.w, v1.x, v1.y, v1.z, v1.w};
#pragma unroll
            for (int kk = 0; kk < 8; ++kk) {
                unsigned pat = p8[kk];
                if ((pat >> 13) == part)
                    atomicAdd(&lh[pat & (BPP - 1)], vsc[kk]);   // ds_add_f32, on-CU
            }
        }
        for (int i = lo + (nvec << 3) + (int)threadIdx.x; i < hi; i += BUILD_BLK) {
            unsigned pat = pats[i];
            if ((pat >> 13) == part)
                atomicAdd(&lh[pat & (BPP - 1)], vals[i]);
        }
    }
    __syncthreads();
    float* dst = part_hists + (size_t)blockIdx.x * BPP;
    for (int b = threadIdx.x; b < BPP; b += BUILD_BLK) dst[b] = lh[b];
}

__global__ void reduce_parts(const float* __restrict__ part_hists, float* __restrict__ final_h) {
    int g = blockIdx.x * blockDim.x + threadIdx.x;   // bin 0..65535
    unsigned part = (unsigned)g >> 13;
    unsigned b = (unsigned)g & (BPP - 1);
    const float* src = part_hists + ((size_t)part * NSLICES) * BPP + b;
    float s = 0.0f;
#pragma unroll 8
    for (int sl = 0; sl < NSLICES; ++sl) s += src[(size_t)sl * BPP];
    final_h[g] = s;
}

// tiny final gather: 4 queries per thread via ushort4 + float4 store
__global__ __launch_bounds__(BLK) void gather_pat(const unsigned short* __restrict__ pq,
                                                  const float* __restrict__ h,
                                                  float* __restrict__ out, int n) {
    int t = blockIdx.x * blockDim.x + threadIdx.x;
    int base = t * 4;
    if (base + 4 <= n) {
        ushort4 p4 = *reinterpret_cast<const ushort4*>(pq + base);
        float4 o;
        o.x = h[p4.x]; o.y = h[p4.y]; o.z = h[p4.z]; o.w = h[p4.w];
        *reinterpret_cast<float4*>(out + base) = o;
    } else {
        for (int i = base; i < n; ++i) out[i] = h[pq[i]];
    }
}

// ---- fallback (R0 path) if workspace too small ----
__global__ void build_hist_dev(const int* __restrict__ coords, const float* __restrict__ vals,
                               float* __restrict__ hist, int n) {
    int i = blockIdx.x * blockDim.x + threadIdx.x;
    if (i >= n) return;
    atomicAdd(&hist[pattern_of(coords + (size_t)i * REL_W)], vals[i]);
}
__global__ void gather_coord(const int* __restrict__ queries, const float* __restrict__ hist,
                             float* __restrict__ out, int n) {
    int i = blockIdx.x * blockDim.x + threadIdx.x;
    if (i >= n) return;
    out[i] = hist[pattern_of(queries + (size_t)i * REL_W)];
}

static inline size_t align_up(size_t x, size_t a) { return (x + a - 1) & ~(a - 1); }

extern "C" void kernel_launch(void* const* d_in, const int* in_sizes, int n_in,
                              void* d_out, int out_size, void* d_ws, size_t ws_size,
                              hipStream_t stream) {
    const int*   stored  = (const int*)d_in[0];   // [N_store, 16] int32
    const int*   queries = (const int*)d_in[1];   // [N_query, 16] int32
    const float* vals    = (const float*)d_in[2]; // [N_store] f32
    float*       out     = (float*)d_out;         // [N_query] f32

    int n_store = in_sizes[0] / REL_W;
    int n_query = in_sizes[1] / REL_W;

    // workspace layout
    size_t off_pat_s = 0;
    size_t off_pat_q = align_up(off_pat_s + (size_t)n_store * 2, 256);
    size_t off_hists = align_up(off_pat_q + (size_t)n_query * 2, 256);
    size_t off_final = off_hists + (size_t)NPART * NSLICES * BPP * sizeof(float);
    size_t need      = off_final + (size_t)NBINS * sizeof(float);

    if (ws_size >= need) {
        unsigned short* pat_s = (unsigned short*)((char*)d_ws + off_pat_s);
        unsigned short* pat_q = (unsigned short*)((char*)d_ws + off_pat_q);
        float* part_hists     = (float*)((char*)d_ws + off_hists);
        float* final_h        = (float*)((char*)d_ws + off_final);

        int tot4    = (n_store + n_query) * 4;
        int eblocks = (tot4 + BLK * EUNROLL - 1) / (BLK * EUNROLL);
        int gblocks = (n_query + BLK * 4 - 1) / (BLK * 4);
        extract_both8<<<eblocks, BLK, 0, stream>>>(stored, queries, pat_s, pat_q, n_store, n_query);
        build_parts<<<NPART * NSLICES, BUILD_BLK, 0, stream>>>(pat_s, vals, part_hists, n_store);
        reduce_parts<<<NBINS / BLK, BLK, 0, stream>>>(part_hists, final_h);
        gather_pat<<<gblocks, BLK, 0, stream>>>(pat_q, final_h, out, n_query);
    } else {
        float* hist = (float*)d_ws;
        hipMemsetAsync(d_ws, 0, NBINS * sizeof(float), stream);
        build_hist_dev<<<(n_store + BLK - 1) / BLK, BLK, 0, stream>>>(stored, vals, hist, n_store);
        gather_coord<<<(n_query + BLK - 1) / BLK, BLK, 0, stream>>>(queries, hist, out, n_query);
    }
}